// Round 7
// baseline (208.070 us; speedup 1.0000x reference)
//
#include <hip/hip_runtime.h>

#define N_NODES 50000
#define N_EDGES 800000
#define DFEAT   128
#define CAP     48     // slots per dst node bucket; Binom(800K,1/50K) tail ~ 2e-6
#define NBINS   256
#define NPB     196    // nodes per bin (255*196=49980; last bin has 20 nodes)
#define BINCAP  3700   // edges per bin; mean 3137, sigma 56 -> +10 sigma
#define CHUNK   4096   // edges per k2a block
#define HBS     (N_NODES * 8)   // u32 per feature-slice of hb

// ---------------------------------------------------------------------------
__device__ __forceinline__ unsigned bf16_rne(float f) {
    unsigned u = __float_as_uint(f);
    return (u + 0x7FFFu + ((u >> 16) & 1u)) >> 16;
}

// ---------------------------------------------------------------------------
// K1: per-node gate dots -> nodetab[i] = {gd, gs, deg, 0}; zero counts + gbin;
// emit bf16 copy of h in SLICE-MAJOR layout: hb[slice*HBS + node*8 + u]
// holds feats {slice*16+2u, slice*16+2u+1} — with slice=lane>>3, u=lane&7
// this is exactly feats {2*lane, 2*lane+1}, i.e. the float2 the lane loads.
// ---------------------------------------------------------------------------
__global__ __launch_bounds__(256) void k1_dots(const float* __restrict__ h,
                                               const float* __restrict__ gate_w,
                                               const float* __restrict__ deg,
                                               float4* __restrict__ nodetab,
                                               int* __restrict__ counts,
                                               unsigned* __restrict__ hb,
                                               int* __restrict__ gbin) {
    if (gbin && blockIdx.x == 0) {
        for (int i = threadIdx.x; i < NBINS; i += 256) gbin[i] = 0;
    }
    int node = (blockIdx.x * 256 + threadIdx.x) >> 6;
    int lane = threadIdx.x & 63;
    if (node >= N_NODES) return;
    const float2* h2 = (const float2*)(h + (size_t)node * DFEAT);
    float2 hv = h2[lane];
    if (hb) {
        unsigned lo = bf16_rne(hv.x);
        unsigned hi = bf16_rne(hv.y);
        int slice = lane >> 3, u = lane & 7;
        hb[(size_t)slice * HBS + node * 8 + u] = lo | (hi << 16);
    }
    float2 wd = ((const float2*)gate_w)[lane];
    float2 ws = ((const float2*)(gate_w + DFEAT))[lane];
    float vd = hv.x * wd.x + hv.y * wd.y;
    float vs = hv.x * ws.x + hv.y * ws.y;
    #pragma unroll
    for (int off = 32; off > 0; off >>= 1) {
        vd += __shfl_down(vd, off, 64);
        vs += __shfl_down(vs, off, 64);
    }
    if (lane == 0) {
        nodetab[node] = make_float4(vd, vs, deg[node], 0.0f);
        counts[node] = 0;
    }
}

// ---------------------------------------------------------------------------
// K2a: edge pass -> per-bin contiguous runs. Packs (s | dlow<<16 | bin<<24,
// w_fp32bits). One global atomic per (block,bin).
// ---------------------------------------------------------------------------
__global__ __launch_bounds__(256) void k2a_bin(const int* __restrict__ src,
                                               const int* __restrict__ dst,
                                               const float4* __restrict__ nodetab,
                                               const float* __restrict__ gate_b,
                                               int* __restrict__ gbin_cnt,
                                               uint2* __restrict__ binned) {
    __shared__ uint2 stage[CHUNK];          // 32 KB
    __shared__ int bcnt[NBINS], bcur[NBINS], gbase[NBINS];
    int tid = threadIdx.x;
    for (int i = tid; i < NBINS; i += 256) { bcnt[i] = 0; bcur[i] = 0; }
    __syncthreads();

    int e0 = blockIdx.x * CHUNK;
    float bb = gate_b[0];
    for (int i = tid; i < CHUNK; i += 256) {
        int e = e0 + i;
        unsigned m = 0xFFFFFFFFu; float w = 0.f;
        if (e < N_EDGES) {
            int s = src[e], d = dst[e];
            float4 ns = nodetab[s];
            float4 nd = nodetab[d];
            float a = tanhf(nd.x + ns.y + bb);      // gd[d] + gs[s] + b
            w = a * nd.z * ns.z;                    // * deg[d] * deg[s]
            int bin  = d / NPB;                     // 0..255
            int dlow = d - bin * NPB;               // 0..195
            m = (unsigned)s | ((unsigned)dlow << 16) | ((unsigned)bin << 24);
            atomicAdd(&bcnt[bin], 1);
        }
        stage[i] = make_uint2(m, __float_as_uint(w));
    }
    __syncthreads();
    for (int i = tid; i < NBINS; i += 256)
        if (bcnt[i] > 0) gbase[i] = atomicAdd(&gbin_cnt[i], bcnt[i]);
    __syncthreads();
    for (int i = tid; i < CHUNK; i += 256) {
        uint2 r = stage[i];
        if (r.x != 0xFFFFFFFFu) {
            int bin = r.x >> 24;
            int pos = atomicAdd(&bcur[bin], 1);
            int idx = gbase[bin] + pos;
            if (idx < BINCAP)
                binned[(size_t)bin * BINCAP + idx] = r;
        }
    }
}

// ---------------------------------------------------------------------------
// K2b: one block per bin. Build node buckets in LDS (LDS atomics), dump
// packed u32 bucket (s:16 | w_bf16:16) + counts, fully coalesced.
// ---------------------------------------------------------------------------
__global__ __launch_bounds__(256) void k2b_bucket(const uint2* __restrict__ binned,
                                                  const int* __restrict__ gbin_cnt,
                                                  unsigned* __restrict__ bucket,
                                                  int* __restrict__ counts) {
    __shared__ int lcnt[NPB];
    __shared__ unsigned lbuck[NPB * CAP];   // 37.6 KB
    int tid = threadIdx.x, bin = blockIdx.x;
    for (int i = tid; i < NPB; i += 256) lcnt[i] = 0;
    __syncthreads();

    int cnt = gbin_cnt[bin]; if (cnt > BINCAP) cnt = BINCAP;
    const uint2* bsrc = binned + (size_t)bin * BINCAP;
    for (int i = tid; i < cnt; i += 256) {
        uint2 r = bsrc[i];
        int dlow = (r.x >> 16) & 0xFF;
        unsigned packed = (r.x & 0xFFFFu) | (bf16_rne(__uint_as_float(r.y)) << 16);
        int pos = atomicAdd(&lcnt[dlow], 1);
        if (pos < CAP) lbuck[dlow * CAP + pos] = packed;
    }
    __syncthreads();

    int nbase = bin * NPB;
    int nvalid = N_NODES - nbase; if (nvalid > NPB) nvalid = NPB;
    for (int i = tid; i < nvalid; i += 256) {
        int c = lcnt[i];
        counts[nbase + i] = (c > CAP) ? CAP : c;
    }
    int limit = nvalid * CAP;
    unsigned* dstp = bucket + (size_t)nbase * CAP;
    for (int i = tid; i < limit; i += 256) dstp[i] = lbuck[i];
}

// ---------------------------------------------------------------------------
// K2 (fallback): direct scatter of packed u32, used only if ws too small.
// ---------------------------------------------------------------------------
__global__ __launch_bounds__(256) void k2_edge(const int* __restrict__ src,
                                               const int* __restrict__ dst,
                                               const float4* __restrict__ nodetab,
                                               const float* __restrict__ gate_b,
                                               int* __restrict__ counts,
                                               unsigned* __restrict__ bucket) {
    int e = blockIdx.x * 256 + threadIdx.x;
    if (e >= N_EDGES) return;
    int s = src[e], d = dst[e];
    float4 ns = nodetab[s];
    float4 nd = nodetab[d];
    float a = tanhf(nd.x + ns.y + gate_b[0]);
    float w = a * nd.z * ns.z;
    int pos = atomicAdd(&counts[d], 1);
    if (pos < CAP)
        bucket[(size_t)d * CAP + pos] = (unsigned)s | (bf16_rne(w) << 16);
}

// ---------------------------------------------------------------------------
// K5 (XCD feature-sliced): block's slice = blockIdx.x & 7 -> with round-robin
// block->XCD dispatch, each XCD touches only its 1.6 MB hb slice (L2-resident).
// Wave layout: lane = eg*8 + u; eg = edge group (8 edges in parallel),
// u = u32 within the 16-feat slice. Per block: 4 waves x 4 nodes = 16 nodes.
// Reduce over eg via shfl_down(32/16/8); lanes 0..7 store 64 B of z.
// ---------------------------------------------------------------------------
__global__ __launch_bounds__(256) void k5_gather_sliced(const unsigned* __restrict__ bucket,
                                                        const int* __restrict__ counts,
                                                        const unsigned* __restrict__ hb,
                                                        float* __restrict__ z) {
    int slice = blockIdx.x & 7;
    int nblk  = blockIdx.x >> 3;          // 0..3124
    int wave  = threadIdx.x >> 6;         // 0..3
    int lane  = threadIdx.x & 63;
    int eg    = lane >> 3;                // 0..7
    int u     = lane & 7;                 // 0..7
    const unsigned* hbs = hb + (size_t)slice * HBS;

    #pragma unroll
    for (int i = 0; i < 4; ++i) {
        int node = nblk * 16 + wave * 4 + i;   // < 50000 by construction
        int cnt = counts[node];
        if (cnt > CAP) cnt = CAP;
        const unsigned* b = bucket + (size_t)node * CAP;
        float ax = 0.f, ay = 0.f;
        int last = cnt - 1;
        for (int p = 0; p < cnt; p += 8) {
            int idx = p + eg;
            int ic = (idx > last) ? last : idx;
            unsigned e = b[ic];
            unsigned q = hbs[(size_t)(e & 0xFFFFu) * 8 + u];
            float w = (idx <= last) ? __uint_as_float(e & 0xFFFF0000u) : 0.f;
            ax += w * __uint_as_float(q << 16);
            ay += w * __uint_as_float(q & 0xFFFF0000u);
        }
        ax += __shfl_down(ax, 32, 64); ay += __shfl_down(ay, 32, 64);
        ax += __shfl_down(ax, 16, 64); ay += __shfl_down(ay, 16, 64);
        ax += __shfl_down(ax, 8, 64);  ay += __shfl_down(ay, 8, 64);
        if (lane < 8)
            ((float2*)z)[(size_t)node * 64 + slice * 8 + u] = make_float2(ax, ay);
    }
}

// ---------------------------------------------------------------------------
// K5 fallback (fp32 h gather, packed u32 bucket), if ws too small for hb.
// ---------------------------------------------------------------------------
__global__ __launch_bounds__(256) void k5_gather_f32(const unsigned* __restrict__ bucket,
                                                     const int* __restrict__ counts,
                                                     const float* __restrict__ h,
                                                     float* __restrict__ z) {
    int node = (blockIdx.x * 256 + threadIdx.x) >> 6;
    int lane = threadIdx.x & 63;
    if (node >= N_NODES) return;
    int half = lane >> 5;
    int fl   = lane & 31;
    int cnt = counts[node];
    if (cnt > CAP) cnt = CAP;
    const unsigned* b = bucket + (size_t)node * CAP;
    const float4* h4 = (const float4*)h;

    float4 a0 = make_float4(0.f,0.f,0.f,0.f);
    float4 a1 = make_float4(0.f,0.f,0.f,0.f);

    int p = 0;
    for (; p + 4 <= cnt; p += 4) {
        unsigned e0 = b[p     + half];
        unsigned e1 = b[p + 2 + half];
        float4 h0 = h4[(size_t)(e0 & 0xFFFFu) * 32 + fl];
        float4 h1 = h4[(size_t)(e1 & 0xFFFFu) * 32 + fl];
        float w0 = __uint_as_float(e0 & 0xFFFF0000u);
        float w1 = __uint_as_float(e1 & 0xFFFF0000u);
        a0.x += w0*h0.x; a0.y += w0*h0.y; a0.z += w0*h0.z; a0.w += w0*h0.w;
        a1.x += w1*h1.x; a1.y += w1*h1.y; a1.z += w1*h1.z; a1.w += w1*h1.w;
    }
    for (; p < cnt; p += 2) {
        int q = p + half;
        if (q < cnt) {
            unsigned e = b[q];
            float4 hv = h4[(size_t)(e & 0xFFFFu) * 32 + fl];
            float w = __uint_as_float(e & 0xFFFF0000u);
            a0.x += w*hv.x; a0.y += w*hv.y; a0.z += w*hv.z; a0.w += w*hv.w;
        }
    }
    a0.x += a1.x; a0.y += a1.y; a0.z += a1.z; a0.w += a1.w;

    float ox = __shfl_down(a0.x, 32, 64);
    float oy = __shfl_down(a0.y, 32, 64);
    float oz = __shfl_down(a0.z, 32, 64);
    float ow = __shfl_down(a0.w, 32, 64);
    if (half == 0) {
        a0.x += ox; a0.y += oy; a0.z += oz; a0.w += ow;
        ((float4*)z)[(size_t)node * 32 + fl] = a0;
    }
}

// ---------------------------------------------------------------------------
extern "C" void kernel_launch(void* const* d_in, const int* in_sizes, int n_in,
                              void* d_out, int out_size, void* d_ws, size_t ws_size,
                              hipStream_t stream) {
    const float* h      = (const float*)d_in[0];
    const float* deg    = (const float*)d_in[1];
    const float* gate_w = (const float*)d_in[2];
    const float* gate_b = (const float*)d_in[3];
    const int*   src    = (const int*)d_in[4];
    const int*   dst    = (const int*)d_in[5];
    float* z = (float*)d_out;

    // workspace layout:
    // nodetab[N]f4 | counts[N]i | bucket[N*CAP]u32 | hb[8*HBS]u32 | gbin[256]i | binned[256*BINCAP]u2
    float4*   nodetab = (float4*)d_ws;                                    //    800,000 B
    int*      counts  = (int*)(nodetab + N_NODES);                        //    200,000 B
    unsigned* bucket  = (unsigned*)(counts + N_NODES);                    //  9,600,000 B
    unsigned* hb      = (unsigned*)(bucket + (size_t)N_NODES * CAP);      // 12,800,000 B
    int*      gbin    = (int*)(hb + (size_t)8 * HBS);                     //      1,024 B
    uint2*    binned  = (uint2*)(gbin + NBINS);                           //  7,577,600 B
    const size_t NEED = 800000u + 200000u + 9600000u + 12800000u + 1024u
                      + (size_t)NBINS * BINCAP * 8u;
    bool full = (ws_size >= NEED);

    int nodeBlocks = (N_NODES * 64 + 255) / 256;        // 12500
    int edgeBlocks = (N_EDGES + 255) / 256;             // 3125
    int binBlocks  = (N_EDGES + CHUNK - 1) / CHUNK;     // 196
    int slcBlocks  = (N_NODES / 16) * 8;                // 25000

    k1_dots<<<nodeBlocks, 256, 0, stream>>>(h, gate_w, deg, nodetab, counts,
                                            full ? hb : nullptr,
                                            full ? gbin : nullptr);
    if (full) {
        k2a_bin<<<binBlocks, 256, 0, stream>>>(src, dst, nodetab, gate_b, gbin, binned);
        k2b_bucket<<<NBINS, 256, 0, stream>>>(binned, gbin, bucket, counts);
        k5_gather_sliced<<<slcBlocks, 256, 0, stream>>>(bucket, counts, hb, z);
    } else {
        k2_edge<<<edgeBlocks, 256, 0, stream>>>(src, dst, nodetab, gate_b,
                                                counts, bucket);
        k5_gather_f32<<<edgeBlocks == 0 ? 1 : nodeBlocks, 256, 0, stream>>>(bucket, counts, h, z);
    }
}

// Round 9
// 154.692 us; speedup vs baseline: 1.3451x; 1.3451x over previous
//
#include <hip/hip_runtime.h>

#define N_NODES 50000
#define N_EDGES 800000
#define DFEAT   128
#define CAP     48     // slots per dst node bucket; Binom(800K,1/50K) tail ~ 2e-6
#define NBINS   256
#define NPB     196    // nodes per bin (255*196=49980; last bin has 20 nodes)
#define BINCAP  3700   // edges per bin; mean 3137, sigma 56 -> +10 sigma
#define CHUNK   4096   // edges per k2a block

typedef float f32x4 __attribute__((ext_vector_type(4)));

// ---------------------------------------------------------------------------
__device__ __forceinline__ unsigned bf16_rne(float f) {
    unsigned u = __float_as_uint(f);
    return (u + 0x7FFFu + ((u >> 16) & 1u)) >> 16;
}

// ---------------------------------------------------------------------------
// K1: per-node gate dots -> nodetab[i] = {gd, gs, deg, 0}; zero counts + gbin;
// emit bf16 copy of h (node-major: hb[node*64 + lane] = feats {2l, 2l+1}).
// One 64-lane wave per node, float2 per lane.
// ---------------------------------------------------------------------------
__global__ __launch_bounds__(256) void k1_dots(const float* __restrict__ h,
                                               const float* __restrict__ gate_w,
                                               const float* __restrict__ deg,
                                               float4* __restrict__ nodetab,
                                               int* __restrict__ counts,
                                               unsigned* __restrict__ hb,
                                               int* __restrict__ gbin) {
    if (gbin && blockIdx.x == 0) {
        for (int i = threadIdx.x; i < NBINS; i += 256) gbin[i] = 0;
    }
    int node = (blockIdx.x * 256 + threadIdx.x) >> 6;
    int lane = threadIdx.x & 63;
    if (node >= N_NODES) return;
    const float2* h2 = (const float2*)(h + (size_t)node * DFEAT);
    float2 hv = h2[lane];
    if (hb) {
        unsigned lo = bf16_rne(hv.x);
        unsigned hi = bf16_rne(hv.y);
        hb[(size_t)node * 64 + lane] = lo | (hi << 16);
    }
    float2 wd = ((const float2*)gate_w)[lane];
    float2 ws = ((const float2*)(gate_w + DFEAT))[lane];
    float vd = hv.x * wd.x + hv.y * wd.y;
    float vs = hv.x * ws.x + hv.y * ws.y;
    #pragma unroll
    for (int off = 32; off > 0; off >>= 1) {
        vd += __shfl_down(vd, off, 64);
        vs += __shfl_down(vs, off, 64);
    }
    if (lane == 0) {
        nodetab[node] = make_float4(vd, vs, deg[node], 0.0f);
        counts[node] = 0;
    }
}

// ---------------------------------------------------------------------------
// K2a: edge pass -> per-bin contiguous runs. Packs (s | dlow<<16 | bin<<24,
// w_fp32bits). One global atomic per (block,bin).
// ---------------------------------------------------------------------------
__global__ __launch_bounds__(256) void k2a_bin(const int* __restrict__ src,
                                               const int* __restrict__ dst,
                                               const float4* __restrict__ nodetab,
                                               const float* __restrict__ gate_b,
                                               int* __restrict__ gbin_cnt,
                                               uint2* __restrict__ binned) {
    __shared__ uint2 stage[CHUNK];          // 32 KB
    __shared__ int bcnt[NBINS], bcur[NBINS], gbase[NBINS];
    int tid = threadIdx.x;
    for (int i = tid; i < NBINS; i += 256) { bcnt[i] = 0; bcur[i] = 0; }
    __syncthreads();

    int e0 = blockIdx.x * CHUNK;
    float bb = gate_b[0];
    for (int i = tid; i < CHUNK; i += 256) {
        int e = e0 + i;
        unsigned m = 0xFFFFFFFFu; float w = 0.f;
        if (e < N_EDGES) {
            int s = src[e], d = dst[e];
            float4 ns = nodetab[s];
            float4 nd = nodetab[d];
            float a = tanhf(nd.x + ns.y + bb);      // gd[d] + gs[s] + b
            w = a * nd.z * ns.z;                    // * deg[d] * deg[s]
            int bin  = d / NPB;                     // 0..255
            int dlow = d - bin * NPB;               // 0..195
            m = (unsigned)s | ((unsigned)dlow << 16) | ((unsigned)bin << 24);
            atomicAdd(&bcnt[bin], 1);
        }
        stage[i] = make_uint2(m, __float_as_uint(w));
    }
    __syncthreads();
    for (int i = tid; i < NBINS; i += 256)
        if (bcnt[i] > 0) gbase[i] = atomicAdd(&gbin_cnt[i], bcnt[i]);
    __syncthreads();
    for (int i = tid; i < CHUNK; i += 256) {
        uint2 r = stage[i];
        if (r.x != 0xFFFFFFFFu) {
            int bin = r.x >> 24;
            int pos = atomicAdd(&bcur[bin], 1);
            int idx = gbase[bin] + pos;
            if (idx < BINCAP)
                binned[(size_t)bin * BINCAP + idx] = r;
        }
    }
}

// ---------------------------------------------------------------------------
// K2b: one block per bin. Build node buckets in LDS (LDS atomics), dump
// packed u32 bucket (s:16 | w_bf16:16) + counts, fully coalesced.
// ---------------------------------------------------------------------------
__global__ __launch_bounds__(256) void k2b_bucket(const uint2* __restrict__ binned,
                                                  const int* __restrict__ gbin_cnt,
                                                  unsigned* __restrict__ bucket,
                                                  int* __restrict__ counts) {
    __shared__ int lcnt[NPB];
    __shared__ unsigned lbuck[NPB * CAP];   // 37.6 KB
    int tid = threadIdx.x, bin = blockIdx.x;
    for (int i = tid; i < NPB; i += 256) lcnt[i] = 0;
    __syncthreads();

    int cnt = gbin_cnt[bin]; if (cnt > BINCAP) cnt = BINCAP;
    const uint2* bsrc = binned + (size_t)bin * BINCAP;
    for (int i = tid; i < cnt; i += 256) {
        uint2 r = bsrc[i];
        int dlow = (r.x >> 16) & 0xFF;
        unsigned packed = (r.x & 0xFFFFu) | (bf16_rne(__uint_as_float(r.y)) << 16);
        int pos = atomicAdd(&lcnt[dlow], 1);
        if (pos < CAP) lbuck[dlow * CAP + pos] = packed;
    }
    __syncthreads();

    int nbase = bin * NPB;
    int nvalid = N_NODES - nbase; if (nvalid > NPB) nvalid = NPB;
    for (int i = tid; i < nvalid; i += 256) {
        int c = lcnt[i];
        counts[nbase + i] = (c > CAP) ? CAP : c;
    }
    int limit = nvalid * CAP;
    unsigned* dstp = bucket + (size_t)nbase * CAP;
    for (int i = tid; i < limit; i += 256) dstp[i] = lbuck[i];
}

// ---------------------------------------------------------------------------
// K2 (fallback): direct scatter of packed u32, used only if ws too small.
// ---------------------------------------------------------------------------
__global__ __launch_bounds__(256) void k2_edge(const int* __restrict__ src,
                                               const int* __restrict__ dst,
                                               const float4* __restrict__ nodetab,
                                               const float* __restrict__ gate_b,
                                               int* __restrict__ counts,
                                               unsigned* __restrict__ bucket) {
    int e = blockIdx.x * 256 + threadIdx.x;
    if (e >= N_EDGES) return;
    int s = src[e], d = dst[e];
    float4 ns = nodetab[s];
    float4 nd = nodetab[d];
    float a = tanhf(nd.x + ns.y + gate_b[0]);
    float w = a * nd.z * ns.z;
    int pos = atomicAdd(&counts[d], 1);
    if (pos < CAP)
        bucket[(size_t)d * CAP + pos] = (unsigned)s | (bf16_rne(w) << 16);
}

// ---------------------------------------------------------------------------
// K5 (bf16 table): per-node gather-accumulate, deep MLP.
// Half-wave owns alternate edges; lane fl covers feats [4fl,4fl+4) via one
// 8B uint2 load. 16 edges / iter (8 independent gathers per lane).
// Clean (clamp-free) full iterations + one clamped remainder iteration.
// ---------------------------------------------------------------------------
__device__ __forceinline__ void bf4_fma(float4& a, float w, uint2 q) {
    a.x += w * __uint_as_float(q.x << 16);
    a.y += w * __uint_as_float(q.x & 0xFFFF0000u);
    a.z += w * __uint_as_float(q.y << 16);
    a.w += w * __uint_as_float(q.y & 0xFFFF0000u);
}

__global__ __launch_bounds__(256) void k5_gather_bf16(const unsigned* __restrict__ bucket,
                                                      const int* __restrict__ counts,
                                                      const unsigned* __restrict__ hb,
                                                      float* __restrict__ z) {
    int node = (blockIdx.x * 256 + threadIdx.x) >> 6;
    int lane = threadIdx.x & 63;
    if (node >= N_NODES) return;
    int half = lane >> 5;
    int fl   = lane & 31;
    int cnt = counts[node];
    if (cnt > CAP) cnt = CAP;
    const unsigned* b = bucket + (size_t)node * CAP;
    const uint2* hb2 = (const uint2*)hb;

    float4 a0 = make_float4(0.f,0.f,0.f,0.f);
    float4 a1 = make_float4(0.f,0.f,0.f,0.f);
    float4 a2 = make_float4(0.f,0.f,0.f,0.f);
    float4 a3 = make_float4(0.f,0.f,0.f,0.f);

    int nfull = cnt & ~15;      // clamp-free region
    int p = 0;
    for (; p < nfull; p += 16) {
        int base = p + half;
        unsigned e0 = b[base], e1 = b[base+2], e2 = b[base+4], e3 = b[base+6];
        unsigned e4 = b[base+8], e5 = b[base+10], e6 = b[base+12], e7 = b[base+14];
        uint2 q0 = hb2[(size_t)(e0 & 0xFFFFu) * 32 + fl];
        uint2 q1 = hb2[(size_t)(e1 & 0xFFFFu) * 32 + fl];
        uint2 q2 = hb2[(size_t)(e2 & 0xFFFFu) * 32 + fl];
        uint2 q3 = hb2[(size_t)(e3 & 0xFFFFu) * 32 + fl];
        uint2 q4 = hb2[(size_t)(e4 & 0xFFFFu) * 32 + fl];
        uint2 q5 = hb2[(size_t)(e5 & 0xFFFFu) * 32 + fl];
        uint2 q6 = hb2[(size_t)(e6 & 0xFFFFu) * 32 + fl];
        uint2 q7 = hb2[(size_t)(e7 & 0xFFFFu) * 32 + fl];
        bf4_fma(a0, __uint_as_float(e0 & 0xFFFF0000u), q0);
        bf4_fma(a1, __uint_as_float(e1 & 0xFFFF0000u), q1);
        bf4_fma(a2, __uint_as_float(e2 & 0xFFFF0000u), q2);
        bf4_fma(a3, __uint_as_float(e3 & 0xFFFF0000u), q3);
        bf4_fma(a0, __uint_as_float(e4 & 0xFFFF0000u), q4);
        bf4_fma(a1, __uint_as_float(e5 & 0xFFFF0000u), q5);
        bf4_fma(a2, __uint_as_float(e6 & 0xFFFF0000u), q6);
        bf4_fma(a3, __uint_as_float(e7 & 0xFFFF0000u), q7);
    }
    if (p < cnt) {              // one clamped remainder iteration (<=15 edges)
        int last = cnt - 1;
        int base = p + half;
        int i0 = base;      if (i0 > last) i0 = last;
        int i1 = base + 2;  if (i1 > last) i1 = last;
        int i2 = base + 4;  if (i2 > last) i2 = last;
        int i3 = base + 6;  if (i3 > last) i3 = last;
        int i4 = base + 8;  if (i4 > last) i4 = last;
        int i5 = base + 10; if (i5 > last) i5 = last;
        int i6 = base + 12; if (i6 > last) i6 = last;
        int i7 = base + 14; if (i7 > last) i7 = last;
        unsigned e0 = b[i0], e1 = b[i1], e2 = b[i2], e3 = b[i3];
        unsigned e4 = b[i4], e5 = b[i5], e6 = b[i6], e7 = b[i7];
        uint2 q0 = hb2[(size_t)(e0 & 0xFFFFu) * 32 + fl];
        uint2 q1 = hb2[(size_t)(e1 & 0xFFFFu) * 32 + fl];
        uint2 q2 = hb2[(size_t)(e2 & 0xFFFFu) * 32 + fl];
        uint2 q3 = hb2[(size_t)(e3 & 0xFFFFu) * 32 + fl];
        uint2 q4 = hb2[(size_t)(e4 & 0xFFFFu) * 32 + fl];
        uint2 q5 = hb2[(size_t)(e5 & 0xFFFFu) * 32 + fl];
        uint2 q6 = hb2[(size_t)(e6 & 0xFFFFu) * 32 + fl];
        uint2 q7 = hb2[(size_t)(e7 & 0xFFFFu) * 32 + fl];
        float w0 = (base      <= last) ? __uint_as_float(e0 & 0xFFFF0000u) : 0.f;
        float w1 = (base + 2  <= last) ? __uint_as_float(e1 & 0xFFFF0000u) : 0.f;
        float w2 = (base + 4  <= last) ? __uint_as_float(e2 & 0xFFFF0000u) : 0.f;
        float w3 = (base + 6  <= last) ? __uint_as_float(e3 & 0xFFFF0000u) : 0.f;
        float w4 = (base + 8  <= last) ? __uint_as_float(e4 & 0xFFFF0000u) : 0.f;
        float w5 = (base + 10 <= last) ? __uint_as_float(e5 & 0xFFFF0000u) : 0.f;
        float w6 = (base + 12 <= last) ? __uint_as_float(e6 & 0xFFFF0000u) : 0.f;
        float w7 = (base + 14 <= last) ? __uint_as_float(e7 & 0xFFFF0000u) : 0.f;
        bf4_fma(a0, w0, q0);
        bf4_fma(a1, w1, q1);
        bf4_fma(a2, w2, q2);
        bf4_fma(a3, w3, q3);
        bf4_fma(a0, w4, q4);
        bf4_fma(a1, w5, q5);
        bf4_fma(a2, w6, q6);
        bf4_fma(a3, w7, q7);
    }

    a0.x += a1.x + a2.x + a3.x;
    a0.y += a1.y + a2.y + a3.y;
    a0.z += a1.z + a2.z + a3.z;
    a0.w += a1.w + a2.w + a3.w;

    float ox = __shfl_down(a0.x, 32, 64);
    float oy = __shfl_down(a0.y, 32, 64);
    float oz = __shfl_down(a0.z, 32, 64);
    float ow = __shfl_down(a0.w, 32, 64);
    if (half == 0) {
        f32x4 v;
        v.x = a0.x + ox; v.y = a0.y + oy; v.z = a0.z + oz; v.w = a0.w + ow;
        __builtin_nontemporal_store(v, (f32x4*)z + (size_t)node * 32 + fl);
    }
}

// ---------------------------------------------------------------------------
// K5 fallback (fp32 h gather, packed u32 bucket), if ws too small for hb.
// ---------------------------------------------------------------------------
__global__ __launch_bounds__(256) void k5_gather_f32(const unsigned* __restrict__ bucket,
                                                     const int* __restrict__ counts,
                                                     const float* __restrict__ h,
                                                     float* __restrict__ z) {
    int node = (blockIdx.x * 256 + threadIdx.x) >> 6;
    int lane = threadIdx.x & 63;
    if (node >= N_NODES) return;
    int half = lane >> 5;
    int fl   = lane & 31;
    int cnt = counts[node];
    if (cnt > CAP) cnt = CAP;
    const unsigned* b = bucket + (size_t)node * CAP;
    const float4* h4 = (const float4*)h;

    float4 a0 = make_float4(0.f,0.f,0.f,0.f);
    float4 a1 = make_float4(0.f,0.f,0.f,0.f);

    int p = 0;
    for (; p + 4 <= cnt; p += 4) {
        unsigned e0 = b[p     + half];
        unsigned e1 = b[p + 2 + half];
        float4 h0 = h4[(size_t)(e0 & 0xFFFFu) * 32 + fl];
        float4 h1 = h4[(size_t)(e1 & 0xFFFFu) * 32 + fl];
        float w0 = __uint_as_float(e0 & 0xFFFF0000u);
        float w1 = __uint_as_float(e1 & 0xFFFF0000u);
        a0.x += w0*h0.x; a0.y += w0*h0.y; a0.z += w0*h0.z; a0.w += w0*h0.w;
        a1.x += w1*h1.x; a1.y += w1*h1.y; a1.z += w1*h1.z; a1.w += w1*h1.w;
    }
    for (; p < cnt; p += 2) {
        int q = p + half;
        if (q < cnt) {
            unsigned e = b[q];
            float4 hv = h4[(size_t)(e & 0xFFFFu) * 32 + fl];
            float w = __uint_as_float(e & 0xFFFF0000u);
            a0.x += w*hv.x; a0.y += w*hv.y; a0.z += w*hv.z; a0.w += w*hv.w;
        }
    }
    a0.x += a1.x; a0.y += a1.y; a0.z += a1.z; a0.w += a1.w;

    float ox = __shfl_down(a0.x, 32, 64);
    float oy = __shfl_down(a0.y, 32, 64);
    float oz = __shfl_down(a0.z, 32, 64);
    float ow = __shfl_down(a0.w, 32, 64);
    if (half == 0) {
        a0.x += ox; a0.y += oy; a0.z += oz; a0.w += ow;
        ((float4*)z)[(size_t)node * 32 + fl] = a0;
    }
}

// ---------------------------------------------------------------------------
extern "C" void kernel_launch(void* const* d_in, const int* in_sizes, int n_in,
                              void* d_out, int out_size, void* d_ws, size_t ws_size,
                              hipStream_t stream) {
    const float* h      = (const float*)d_in[0];
    const float* deg    = (const float*)d_in[1];
    const float* gate_w = (const float*)d_in[2];
    const float* gate_b = (const float*)d_in[3];
    const int*   src    = (const int*)d_in[4];
    const int*   dst    = (const int*)d_in[5];
    float* z = (float*)d_out;

    // workspace layout:
    // nodetab[N]f4 | counts[N]i | bucket[N*CAP]u32 | hb[N*64]u32 | gbin[256]i | binned[256*BINCAP]u2
    float4*   nodetab = (float4*)d_ws;                                    //    800,000 B
    int*      counts  = (int*)(nodetab + N_NODES);                        //    200,000 B
    unsigned* bucket  = (unsigned*)(counts + N_NODES);                    //  9,600,000 B
    unsigned* hb      = (unsigned*)(bucket + (size_t)N_NODES * CAP);      // 12,800,000 B
    int*      gbin    = (int*)(hb + (size_t)N_NODES * 64);                //      1,024 B
    uint2*    binned  = (uint2*)(gbin + NBINS);                           //  7,577,600 B
    const size_t NEED_BF16 = 800000u + 200000u + 9600000u + 12800000u;
    const size_t NEED_BIN  = NEED_BF16 + 1024u + (size_t)NBINS * BINCAP * 8u;
    bool use_bf16 = (ws_size >= NEED_BF16);
    bool use_bin  = (ws_size >= NEED_BIN);

    int nodeBlocks = (N_NODES * 64 + 255) / 256;        // 12500
    int edgeBlocks = (N_EDGES + 255) / 256;             // 3125
    int binBlocks  = (N_EDGES + CHUNK - 1) / CHUNK;     // 196

    k1_dots<<<nodeBlocks, 256, 0, stream>>>(h, gate_w, deg, nodetab, counts,
                                            use_bf16 ? hb : nullptr,
                                            use_bin ? gbin : nullptr);
    if (use_bin) {
        k2a_bin<<<binBlocks, 256, 0, stream>>>(src, dst, nodetab, gate_b, gbin, binned);
        k2b_bucket<<<NBINS, 256, 0, stream>>>(binned, gbin, bucket, counts);
    } else {
        k2_edge<<<edgeBlocks, 256, 0, stream>>>(src, dst, nodetab, gate_b,
                                                counts, bucket);
    }
    if (use_bf16)
        k5_gather_bf16<<<nodeBlocks, 256, 0, stream>>>(bucket, counts, hb, z);
    else
        k5_gather_f32<<<nodeBlocks, 256, 0, stream>>>(bucket, counts, h, z);
}

// Round 10
// 149.050 us; speedup vs baseline: 1.3960x; 1.0379x over previous
//
#include <hip/hip_runtime.h>

#define N_NODES 50000
#define N_EDGES 800000
#define DFEAT   128
#define CAP     48     // slots per dst node bucket; Binom(800K,1/50K) tail ~ 2e-6
#define NBINS   512    // bins; bin = dst / NPB (bins 0..510 used)
#define NPB     98     // nodes per bin (511*98 > 50000)
#define BINCAP  2000   // edges per bin; mean 1562, sigma 40 -> +11 sigma
#define CHUNK   4096   // edges per k2a block

typedef float f32x4 __attribute__((ext_vector_type(4)));

// ---------------------------------------------------------------------------
__device__ __forceinline__ unsigned bf16_rne(float f) {
    unsigned u = __float_as_uint(f);
    return (u + 0x7FFFu + ((u >> 16) & 1u)) >> 16;
}

// ---------------------------------------------------------------------------
// K1: per-node gate dots -> nodetab[i] = {gd, gs, deg, 0}; zero counts + gbin;
// emit bf16 copy of h (node-major: hb[node*64 + lane] = feats {2l, 2l+1}).
// ---------------------------------------------------------------------------
__global__ __launch_bounds__(256) void k1_dots(const float* __restrict__ h,
                                               const float* __restrict__ gate_w,
                                               const float* __restrict__ deg,
                                               float4* __restrict__ nodetab,
                                               int* __restrict__ counts,
                                               unsigned* __restrict__ hb,
                                               int* __restrict__ gbin) {
    if (gbin && blockIdx.x == 0) {
        for (int i = threadIdx.x; i < NBINS; i += 256) gbin[i] = 0;
    }
    int node = (blockIdx.x * 256 + threadIdx.x) >> 6;
    int lane = threadIdx.x & 63;
    if (node >= N_NODES) return;
    const float2* h2 = (const float2*)(h + (size_t)node * DFEAT);
    float2 hv = h2[lane];
    if (hb) {
        unsigned lo = bf16_rne(hv.x);
        unsigned hi = bf16_rne(hv.y);
        hb[(size_t)node * 64 + lane] = lo | (hi << 16);
    }
    float2 wd = ((const float2*)gate_w)[lane];
    float2 ws = ((const float2*)(gate_w + DFEAT))[lane];
    float vd = hv.x * wd.x + hv.y * wd.y;
    float vs = hv.x * ws.x + hv.y * ws.y;
    #pragma unroll
    for (int off = 32; off > 0; off >>= 1) {
        vd += __shfl_down(vd, off, 64);
        vs += __shfl_down(vs, off, 64);
    }
    if (lane == 0) {
        nodetab[node] = make_float4(vd, vs, deg[node], 0.0f);
        counts[node] = 0;
    }
}

// ---------------------------------------------------------------------------
// K2a: edge pass -> per-bin contiguous runs. Packs
// (s | dlow<<16 | bin<<23, w_fp32bits): s 16b, dlow 7b (<98), bin 9b (<511).
// One global atomic per (block,bin).
// ---------------------------------------------------------------------------
__global__ __launch_bounds__(256) void k2a_bin(const int* __restrict__ src,
                                               const int* __restrict__ dst,
                                               const float4* __restrict__ nodetab,
                                               const float* __restrict__ gate_b,
                                               int* __restrict__ gbin_cnt,
                                               uint2* __restrict__ binned) {
    __shared__ uint2 stage[CHUNK];          // 32 KB
    __shared__ int bcnt[NBINS], bcur[NBINS], gbase[NBINS];  // 6 KB
    int tid = threadIdx.x;
    for (int i = tid; i < NBINS; i += 256) { bcnt[i] = 0; bcur[i] = 0; }
    __syncthreads();

    int e0 = blockIdx.x * CHUNK;
    float bb = gate_b[0];
    for (int i = tid; i < CHUNK; i += 256) {
        int e = e0 + i;
        unsigned m = 0xFFFFFFFFu; float w = 0.f;
        if (e < N_EDGES) {
            int s = src[e], d = dst[e];
            float4 ns = nodetab[s];
            float4 nd = nodetab[d];
            float a = tanhf(nd.x + ns.y + bb);      // gd[d] + gs[s] + b
            w = a * nd.z * ns.z;                    // * deg[d] * deg[s]
            int bin  = d / NPB;                     // 0..510
            int dlow = d - bin * NPB;               // 0..97
            m = (unsigned)s | ((unsigned)dlow << 16) | ((unsigned)bin << 23);
            atomicAdd(&bcnt[bin], 1);
        }
        stage[i] = make_uint2(m, __float_as_uint(w));
    }
    __syncthreads();
    for (int i = tid; i < NBINS; i += 256)
        if (bcnt[i] > 0) gbase[i] = atomicAdd(&gbin_cnt[i], bcnt[i]);
    __syncthreads();
    for (int i = tid; i < CHUNK; i += 256) {
        uint2 r = stage[i];
        if (r.x != 0xFFFFFFFFu) {
            int bin = r.x >> 23;
            int pos = atomicAdd(&bcur[bin], 1);
            int idx = gbase[bin] + pos;
            if (idx < BINCAP)
                binned[(size_t)bin * BINCAP + idx] = r;
        }
    }
}

// ---------------------------------------------------------------------------
// K3 (fused k2b+k5): one 512-thread block per bin.
// Phase 1: build the bin's 98 node-buckets in LDS (LDS atomics), packed
//          u32 (s:16 | w_bf16:16).
// Phase 2: gather directly from the LDS buckets — no global bucket at all.
//          Wave w handles nodes w, w+8, ... Deep-MLP loop: half-wave owns
//          alternate edges, lane fl covers feats [4fl,4fl+4) via 8B uint2,
//          16 edges / iter (8 independent hb gathers per lane).
// LDS 19.2 KB -> 2 blocks/CU -> 16 waves/CU during the gather.
// ---------------------------------------------------------------------------
__global__ __launch_bounds__(512) void k3_bucket_gather(const uint2* __restrict__ binned,
                                                        const int* __restrict__ gbin_cnt,
                                                        const unsigned* __restrict__ hb,
                                                        float* __restrict__ z) {
    __shared__ int lcnt[NPB];
    __shared__ unsigned lbuck[NPB * CAP];   // 18.4 KB
    int tid = threadIdx.x, bin = blockIdx.x;
    int nbase = bin * NPB;
    int nvalid = N_NODES - nbase;
    if (nvalid > NPB) nvalid = NPB;
    if (nvalid <= 0) return;                // bin 511: empty

    for (int i = tid; i < NPB; i += 512) lcnt[i] = 0;
    __syncthreads();

    int cnt = gbin_cnt[bin]; if (cnt > BINCAP) cnt = BINCAP;
    const uint2* bsrc = binned + (size_t)bin * BINCAP;
    for (int i = tid; i < cnt; i += 512) {
        uint2 r = bsrc[i];
        int dlow = (r.x >> 16) & 0x7F;
        unsigned packed = (r.x & 0xFFFFu) | (bf16_rne(__uint_as_float(r.y)) << 16);
        int pos = atomicAdd(&lcnt[dlow], 1);
        if (pos < CAP) lbuck[dlow * CAP + pos] = packed;
    }
    __syncthreads();

    int wave = tid >> 6;        // 0..7
    int lane = tid & 63;
    int half = lane >> 5;
    int fl   = lane & 31;
    const uint2* hb2 = (const uint2*)hb;

    for (int n = wave; n < nvalid; n += 8) {
        int c = lcnt[n]; if (c > CAP) c = CAP;
        const unsigned* b = lbuck + n * CAP;

        float4 a0 = make_float4(0.f,0.f,0.f,0.f);
        float4 a1 = make_float4(0.f,0.f,0.f,0.f);
        float4 a2 = make_float4(0.f,0.f,0.f,0.f);
        float4 a3 = make_float4(0.f,0.f,0.f,0.f);

        int nfull = c & ~15;
        int p = 0;
        for (; p < nfull; p += 16) {
            int base = p + half;
            unsigned e0 = b[base], e1 = b[base+2], e2 = b[base+4], e3 = b[base+6];
            unsigned e4 = b[base+8], e5 = b[base+10], e6 = b[base+12], e7 = b[base+14];
            uint2 q0 = hb2[(size_t)(e0 & 0xFFFFu) * 32 + fl];
            uint2 q1 = hb2[(size_t)(e1 & 0xFFFFu) * 32 + fl];
            uint2 q2 = hb2[(size_t)(e2 & 0xFFFFu) * 32 + fl];
            uint2 q3 = hb2[(size_t)(e3 & 0xFFFFu) * 32 + fl];
            uint2 q4 = hb2[(size_t)(e4 & 0xFFFFu) * 32 + fl];
            uint2 q5 = hb2[(size_t)(e5 & 0xFFFFu) * 32 + fl];
            uint2 q6 = hb2[(size_t)(e6 & 0xFFFFu) * 32 + fl];
            uint2 q7 = hb2[(size_t)(e7 & 0xFFFFu) * 32 + fl];
            a0.x += __uint_as_float(e0 & 0xFFFF0000u) * __uint_as_float(q0.x << 16);
            a0.y += __uint_as_float(e0 & 0xFFFF0000u) * __uint_as_float(q0.x & 0xFFFF0000u);
            a0.z += __uint_as_float(e0 & 0xFFFF0000u) * __uint_as_float(q0.y << 16);
            a0.w += __uint_as_float(e0 & 0xFFFF0000u) * __uint_as_float(q0.y & 0xFFFF0000u);
            a1.x += __uint_as_float(e1 & 0xFFFF0000u) * __uint_as_float(q1.x << 16);
            a1.y += __uint_as_float(e1 & 0xFFFF0000u) * __uint_as_float(q1.x & 0xFFFF0000u);
            a1.z += __uint_as_float(e1 & 0xFFFF0000u) * __uint_as_float(q1.y << 16);
            a1.w += __uint_as_float(e1 & 0xFFFF0000u) * __uint_as_float(q1.y & 0xFFFF0000u);
            a2.x += __uint_as_float(e2 & 0xFFFF0000u) * __uint_as_float(q2.x << 16);
            a2.y += __uint_as_float(e2 & 0xFFFF0000u) * __uint_as_float(q2.x & 0xFFFF0000u);
            a2.z += __uint_as_float(e2 & 0xFFFF0000u) * __uint_as_float(q2.y << 16);
            a2.w += __uint_as_float(e2 & 0xFFFF0000u) * __uint_as_float(q2.y & 0xFFFF0000u);
            a3.x += __uint_as_float(e3 & 0xFFFF0000u) * __uint_as_float(q3.x << 16);
            a3.y += __uint_as_float(e3 & 0xFFFF0000u) * __uint_as_float(q3.x & 0xFFFF0000u);
            a3.z += __uint_as_float(e3 & 0xFFFF0000u) * __uint_as_float(q3.y << 16);
            a3.w += __uint_as_float(e3 & 0xFFFF0000u) * __uint_as_float(q3.y & 0xFFFF0000u);
            a0.x += __uint_as_float(e4 & 0xFFFF0000u) * __uint_as_float(q4.x << 16);
            a0.y += __uint_as_float(e4 & 0xFFFF0000u) * __uint_as_float(q4.x & 0xFFFF0000u);
            a0.z += __uint_as_float(e4 & 0xFFFF0000u) * __uint_as_float(q4.y << 16);
            a0.w += __uint_as_float(e4 & 0xFFFF0000u) * __uint_as_float(q4.y & 0xFFFF0000u);
            a1.x += __uint_as_float(e5 & 0xFFFF0000u) * __uint_as_float(q5.x << 16);
            a1.y += __uint_as_float(e5 & 0xFFFF0000u) * __uint_as_float(q5.x & 0xFFFF0000u);
            a1.z += __uint_as_float(e5 & 0xFFFF0000u) * __uint_as_float(q5.y << 16);
            a1.w += __uint_as_float(e5 & 0xFFFF0000u) * __uint_as_float(q5.y & 0xFFFF0000u);
            a2.x += __uint_as_float(e6 & 0xFFFF0000u) * __uint_as_float(q6.x << 16);
            a2.y += __uint_as_float(e6 & 0xFFFF0000u) * __uint_as_float(q6.x & 0xFFFF0000u);
            a2.z += __uint_as_float(e6 & 0xFFFF0000u) * __uint_as_float(q6.y << 16);
            a2.w += __uint_as_float(e6 & 0xFFFF0000u) * __uint_as_float(q6.y & 0xFFFF0000u);
            a3.x += __uint_as_float(e7 & 0xFFFF0000u) * __uint_as_float(q7.x << 16);
            a3.y += __uint_as_float(e7 & 0xFFFF0000u) * __uint_as_float(q7.x & 0xFFFF0000u);
            a3.z += __uint_as_float(e7 & 0xFFFF0000u) * __uint_as_float(q7.y << 16);
            a3.w += __uint_as_float(e7 & 0xFFFF0000u) * __uint_as_float(q7.y & 0xFFFF0000u);
        }
        if (p < c) {            // clamped remainder (<=15 edges)
            int last = c - 1;
            int base = p + half;
            int i0 = base;      if (i0 > last) i0 = last;
            int i1 = base + 2;  if (i1 > last) i1 = last;
            int i2 = base + 4;  if (i2 > last) i2 = last;
            int i3 = base + 6;  if (i3 > last) i3 = last;
            int i4 = base + 8;  if (i4 > last) i4 = last;
            int i5 = base + 10; if (i5 > last) i5 = last;
            int i6 = base + 12; if (i6 > last) i6 = last;
            int i7 = base + 14; if (i7 > last) i7 = last;
            unsigned e0 = b[i0], e1 = b[i1], e2 = b[i2], e3 = b[i3];
            unsigned e4 = b[i4], e5 = b[i5], e6 = b[i6], e7 = b[i7];
            uint2 q0 = hb2[(size_t)(e0 & 0xFFFFu) * 32 + fl];
            uint2 q1 = hb2[(size_t)(e1 & 0xFFFFu) * 32 + fl];
            uint2 q2 = hb2[(size_t)(e2 & 0xFFFFu) * 32 + fl];
            uint2 q3 = hb2[(size_t)(e3 & 0xFFFFu) * 32 + fl];
            uint2 q4 = hb2[(size_t)(e4 & 0xFFFFu) * 32 + fl];
            uint2 q5 = hb2[(size_t)(e5 & 0xFFFFu) * 32 + fl];
            uint2 q6 = hb2[(size_t)(e6 & 0xFFFFu) * 32 + fl];
            uint2 q7 = hb2[(size_t)(e7 & 0xFFFFu) * 32 + fl];
            float w0 = (base      <= last) ? __uint_as_float(e0 & 0xFFFF0000u) : 0.f;
            float w1 = (base + 2  <= last) ? __uint_as_float(e1 & 0xFFFF0000u) : 0.f;
            float w2 = (base + 4  <= last) ? __uint_as_float(e2 & 0xFFFF0000u) : 0.f;
            float w3 = (base + 6  <= last) ? __uint_as_float(e3 & 0xFFFF0000u) : 0.f;
            float w4 = (base + 8  <= last) ? __uint_as_float(e4 & 0xFFFF0000u) : 0.f;
            float w5 = (base + 10 <= last) ? __uint_as_float(e5 & 0xFFFF0000u) : 0.f;
            float w6 = (base + 12 <= last) ? __uint_as_float(e6 & 0xFFFF0000u) : 0.f;
            float w7 = (base + 14 <= last) ? __uint_as_float(e7 & 0xFFFF0000u) : 0.f;
            a0.x += w0 * __uint_as_float(q0.x << 16);
            a0.y += w0 * __uint_as_float(q0.x & 0xFFFF0000u);
            a0.z += w0 * __uint_as_float(q0.y << 16);
            a0.w += w0 * __uint_as_float(q0.y & 0xFFFF0000u);
            a1.x += w1 * __uint_as_float(q1.x << 16);
            a1.y += w1 * __uint_as_float(q1.x & 0xFFFF0000u);
            a1.z += w1 * __uint_as_float(q1.y << 16);
            a1.w += w1 * __uint_as_float(q1.y & 0xFFFF0000u);
            a2.x += w2 * __uint_as_float(q2.x << 16);
            a2.y += w2 * __uint_as_float(q2.x & 0xFFFF0000u);
            a2.z += w2 * __uint_as_float(q2.y << 16);
            a2.w += w2 * __uint_as_float(q2.y & 0xFFFF0000u);
            a3.x += w3 * __uint_as_float(q3.x << 16);
            a3.y += w3 * __uint_as_float(q3.x & 0xFFFF0000u);
            a3.z += w3 * __uint_as_float(q3.y << 16);
            a3.w += w3 * __uint_as_float(q3.y & 0xFFFF0000u);
            a0.x += w4 * __uint_as_float(q4.x << 16);
            a0.y += w4 * __uint_as_float(q4.x & 0xFFFF0000u);
            a0.z += w4 * __uint_as_float(q4.y << 16);
            a0.w += w4 * __uint_as_float(q4.y & 0xFFFF0000u);
            a1.x += w5 * __uint_as_float(q5.x << 16);
            a1.y += w5 * __uint_as_float(q5.x & 0xFFFF0000u);
            a1.z += w5 * __uint_as_float(q5.y << 16);
            a1.w += w5 * __uint_as_float(q5.y & 0xFFFF0000u);
            a2.x += w6 * __uint_as_float(q6.x << 16);
            a2.y += w6 * __uint_as_float(q6.x & 0xFFFF0000u);
            a2.z += w6 * __uint_as_float(q6.y << 16);
            a2.w += w6 * __uint_as_float(q6.y & 0xFFFF0000u);
            a3.x += w7 * __uint_as_float(q7.x << 16);
            a3.y += w7 * __uint_as_float(q7.x & 0xFFFF0000u);
            a3.z += w7 * __uint_as_float(q7.y << 16);
            a3.w += w7 * __uint_as_float(q7.y & 0xFFFF0000u);
        }

        a0.x += a1.x + a2.x + a3.x;
        a0.y += a1.y + a2.y + a3.y;
        a0.z += a1.z + a2.z + a3.z;
        a0.w += a1.w + a2.w + a3.w;

        float ox = __shfl_down(a0.x, 32, 64);
        float oy = __shfl_down(a0.y, 32, 64);
        float oz = __shfl_down(a0.z, 32, 64);
        float ow = __shfl_down(a0.w, 32, 64);
        if (half == 0) {
            f32x4 v;
            v.x = a0.x + ox; v.y = a0.y + oy; v.z = a0.z + oz; v.w = a0.w + ow;
            __builtin_nontemporal_store(v, (f32x4*)z + (size_t)(nbase + n) * 32 + fl);
        }
    }
}

// ---------------------------------------------------------------------------
// Fallbacks (used only if workspace too small): direct scatter + fp32 gather.
// ---------------------------------------------------------------------------
__global__ __launch_bounds__(256) void k2_edge(const int* __restrict__ src,
                                               const int* __restrict__ dst,
                                               const float4* __restrict__ nodetab,
                                               const float* __restrict__ gate_b,
                                               int* __restrict__ counts,
                                               unsigned* __restrict__ bucket) {
    int e = blockIdx.x * 256 + threadIdx.x;
    if (e >= N_EDGES) return;
    int s = src[e], d = dst[e];
    float4 ns = nodetab[s];
    float4 nd = nodetab[d];
    float a = tanhf(nd.x + ns.y + gate_b[0]);
    float w = a * nd.z * ns.z;
    int pos = atomicAdd(&counts[d], 1);
    if (pos < CAP)
        bucket[(size_t)d * CAP + pos] = (unsigned)s | (bf16_rne(w) << 16);
}

__global__ __launch_bounds__(256) void k5_gather_f32(const unsigned* __restrict__ bucket,
                                                     const int* __restrict__ counts,
                                                     const float* __restrict__ h,
                                                     float* __restrict__ z) {
    int node = (blockIdx.x * 256 + threadIdx.x) >> 6;
    int lane = threadIdx.x & 63;
    if (node >= N_NODES) return;
    int half = lane >> 5;
    int fl   = lane & 31;
    int cnt = counts[node];
    if (cnt > CAP) cnt = CAP;
    const unsigned* b = bucket + (size_t)node * CAP;
    const float4* h4 = (const float4*)h;

    float4 a0 = make_float4(0.f,0.f,0.f,0.f);
    float4 a1 = make_float4(0.f,0.f,0.f,0.f);

    int p = 0;
    for (; p + 4 <= cnt; p += 4) {
        unsigned e0 = b[p     + half];
        unsigned e1 = b[p + 2 + half];
        float4 h0 = h4[(size_t)(e0 & 0xFFFFu) * 32 + fl];
        float4 h1 = h4[(size_t)(e1 & 0xFFFFu) * 32 + fl];
        float w0 = __uint_as_float(e0 & 0xFFFF0000u);
        float w1 = __uint_as_float(e1 & 0xFFFF0000u);
        a0.x += w0*h0.x; a0.y += w0*h0.y; a0.z += w0*h0.z; a0.w += w0*h0.w;
        a1.x += w1*h1.x; a1.y += w1*h1.y; a1.z += w1*h1.z; a1.w += w1*h1.w;
    }
    for (; p < cnt; p += 2) {
        int q = p + half;
        if (q < cnt) {
            unsigned e = b[q];
            float4 hv = h4[(size_t)(e & 0xFFFFu) * 32 + fl];
            float w = __uint_as_float(e & 0xFFFF0000u);
            a0.x += w*hv.x; a0.y += w*hv.y; a0.z += w*hv.z; a0.w += w*hv.w;
        }
    }
    a0.x += a1.x; a0.y += a1.y; a0.z += a1.z; a0.w += a1.w;

    float ox = __shfl_down(a0.x, 32, 64);
    float oy = __shfl_down(a0.y, 32, 64);
    float oz = __shfl_down(a0.z, 32, 64);
    float ow = __shfl_down(a0.w, 32, 64);
    if (half == 0) {
        a0.x += ox; a0.y += oy; a0.z += oz; a0.w += ow;
        ((float4*)z)[(size_t)node * 32 + fl] = a0;
    }
}

// ---------------------------------------------------------------------------
extern "C" void kernel_launch(void* const* d_in, const int* in_sizes, int n_in,
                              void* d_out, int out_size, void* d_ws, size_t ws_size,
                              hipStream_t stream) {
    const float* h      = (const float*)d_in[0];
    const float* deg    = (const float*)d_in[1];
    const float* gate_w = (const float*)d_in[2];
    const float* gate_b = (const float*)d_in[3];
    const int*   src    = (const int*)d_in[4];
    const int*   dst    = (const int*)d_in[5];
    float* z = (float*)d_out;

    // workspace layout:
    // nodetab[N]f4 | counts[N]i | bucket[N*CAP]u32 (fallback only) |
    // hb[N*64]u32 | gbin[NBINS]i | binned[NBINS*BINCAP]u2
    float4*   nodetab = (float4*)d_ws;                                    //    800,000 B
    int*      counts  = (int*)(nodetab + N_NODES);                        //    200,000 B
    unsigned* bucket  = (unsigned*)(counts + N_NODES);                    //  9,600,000 B
    unsigned* hb      = (unsigned*)(bucket + (size_t)N_NODES * CAP);      // 12,800,000 B
    int*      gbin    = (int*)(hb + (size_t)N_NODES * 64);                //      2,048 B
    uint2*    binned  = (uint2*)(gbin + NBINS);                           //  8,192,000 B
    const size_t NEED = 800000u + 200000u + 9600000u + 12800000u + 2048u
                      + (size_t)NBINS * BINCAP * 8u;
    bool full = (ws_size >= NEED);

    int nodeBlocks = (N_NODES * 64 + 255) / 256;        // 12500
    int edgeBlocks = (N_EDGES + 255) / 256;             // 3125
    int binBlocks  = (N_EDGES + CHUNK - 1) / CHUNK;     // 196

    k1_dots<<<nodeBlocks, 256, 0, stream>>>(h, gate_w, deg, nodetab, counts,
                                            full ? hb : nullptr,
                                            full ? gbin : nullptr);
    if (full) {
        k2a_bin<<<binBlocks, 256, 0, stream>>>(src, dst, nodetab, gate_b, gbin, binned);
        k3_bucket_gather<<<NBINS, 512, 0, stream>>>(binned, gbin, hb, z);
    } else {
        k2_edge<<<edgeBlocks, 256, 0, stream>>>(src, dst, nodetab, gate_b,
                                                counts, bucket);
        k5_gather_f32<<<nodeBlocks, 256, 0, stream>>>(bucket, counts, h, z);
    }
}